// Round 5
// baseline (461.881 us; speedup 1.0000x reference)
//
#include <hip/hip_runtime.h>

// MADE / PixelCNN autoregressive inverse (all fp32, per reference).
//
// Rounds 0-4 post-mortem: four different inner-loop implementations (spill
// fix, weight pinning, LDS-broadcast removal) all landed at ~179-183 us =
// ~6700 cy/pixel. The invariant was the skeleton: 6 __syncthreads per pixel
// across 16 waves (~700 cy each) + short LDS round-trips. Barrier-bound.
//
// Round-8 restructure: 256 threads = 4 waves = (role: h0+W1 | W2+out) x
// (net: mu | lv), lane = ch. The two nets are independent pipelines; within
// a net every 64-dot is done intra-wave via v_readlane broadcast chains
// (2 instr/MAC), ordered by lgkmcnt only. Cross-wave handoffs: h1(p)
// (role0 -> role1, barrier B1) and mu/ls -> y (role1 -> role0, barrier B2,
// parity-double-buffered xchg). 2 barriers/pixel instead of 6; 4-wave
// barriers are much cheaper than 16-wave. role1 computes W2's off-center
// taps (inputs: h1 at pixels < p) concurrently with role0's long phase.
// With 4 waves/CU each wave has a SIMD to itself: waves_per_eu(1,1) gives
// the full 512-VGPR budget, so each thread keeps its whole weight rows
// (4x64 off-center + 64 center + 16 aux ~ 340 regs) statically indexed.

#define NT 256

__device__ __forceinline__ float elu(float x) { return x > 0.f ? x : expm1f(x); }

__device__ __forceinline__ float rdlane(float v, int l) {
  return __int_as_float(__builtin_amdgcn_readlane(__float_as_int(v), l));
}

__global__ __launch_bounds__(NT)
__attribute__((amdgpu_waves_per_eu(1, 1)))
void made_ar_decode_k(
    const float* __restrict__ x,
    const float* __restrict__ mw0, const float* __restrict__ mb0,
    const float* __restrict__ mw1, const float* __restrict__ mb1,
    const float* __restrict__ mw2, const float* __restrict__ mb2,
    const float* __restrict__ mwo, const float* __restrict__ mbo,
    const float* __restrict__ lw0, const float* __restrict__ lb0,
    const float* __restrict__ lw1, const float* __restrict__ lb1,
    const float* __restrict__ lw2, const float* __restrict__ lb2,
    const float* __restrict__ lwo, const float* __restrict__ lbo,
    float* __restrict__ out)
{
  const int b    = blockIdx.x;
  const int tid  = threadIdx.x;
  const int wave = tid >> 6;        // 0..3
  const int role = wave >> 1;       // 0: h0 + W1 (produces h1); 1: W2 + out
  const int net  = wave & 1;        // 0 = mu, 1 = lv
  const int ch   = tid & 63;        // lane == channel

  // Row caches, parity double-buffered by row. Col index = spatial col + 1,
  // pads at 0 and 9 stay zero ('SAME' border). Rows of parity (i-1)&1 hold
  // row i-1 while row i (parity i&1) is being written.
  __shared__ __align__(16) float h0row[2][2][10][64]; // [net][par][col+1][ch]
  __shared__ __align__(16) float h1row[2][2][10][64];
  __shared__ __align__(16) float yb[2][9][10][4];     // [net][row+1][col+1][c]
  __shared__ __align__(16) float xchg[2][2][4];       // [p&1][net][c] raw out sums
  __shared__ float xls[256];

  for (int k = tid; k < 2*2*10*64; k += NT) {
    (&h0row[0][0][0][0])[k] = 0.f;
    (&h1row[0][0][0][0])[k] = 0.f;
  }
  for (int k = tid; k < 2*9*10*4; k += NT) (&yb[0][0][0][0])[k] = 0.f;
  xls[tid] = x[b*256 + tid];        // [c][i][j] flat = c*64 + p

  // ---- per-thread register weights ----
  // role0: wt = W1 off-center cols, wc = W1 center col, waux = w0 row (16)
  // role1: wt = W2 off-center cols, wc = W2 center col, waux[0..3] = wo col
  const int KH[4] = {0,0,0,1};      // NW, N, NE, W
  const int KW[4] = {0,1,2,0};
  float wt[4][64], wc[64], waux[16];
  float bA = 0.f, bB = 0.f, boM[4], boL[4];
  {
    const float* wg = role ? (net ? lw2 : mw2) : (net ? lw1 : mw1);
#pragma unroll
    for (int t = 0; t < 4; ++t)
#pragma unroll
      for (int q = 0; q < 64; ++q)
        wt[t][q] = wg[((ch*64 + q)*3 + KH[t])*3 + KW[t]];
#pragma unroll
    for (int q = 0; q < 64; ++q) wc[q] = wg[((ch*64 + q)*3 + 1)*3 + 1];
    if (role == 0) {
      const float* w0g = net ? lw0 : mw0;
#pragma unroll
      for (int t = 0; t < 4; ++t)
#pragma unroll
        for (int ic = 0; ic < 4; ++ic)
          waux[t*4 + ic] = w0g[((ch*4 + ic)*3 + KH[t])*3 + KW[t]];
      bA = (net ? lb0 : mb0)[ch];
      bB = (net ? lb1 : mb1)[ch];
    } else {
      const float* wog = net ? lwo : mwo;
#pragma unroll
      for (int c = 0; c < 4; ++c) waux[c] = wog[c*64 + ch];
#pragma unroll
      for (int c = 4; c < 16; ++c) waux[c] = 0.f;
      bA = (net ? lb2 : mb2)[ch];
    }
#pragma unroll
    for (int c = 0; c < 4; ++c) { boM[c] = mbo[c]; boL[c] = lbo[c]; }
  }
  // Pin weights in registers (loads must not be sunk into the pixel loop).
#pragma unroll
  for (int t = 0; t < 4; ++t)
#pragma unroll
    for (int q = 0; q < 64; ++q) asm volatile("" : "+v"(wt[t][q]));
#pragma unroll
  for (int q = 0; q < 64; ++q) asm volatile("" : "+v"(wc[q]));
#pragma unroll
  for (int k = 0; k < 16; ++k) asm volatile("" : "+v"(waux[k]));

  __syncthreads();

  float lsacc  = 0.f;
  float offacc = 0.f;   // role1: W2 off-center partial, carried across B1

#pragma unroll 1
  for (int p = 0; p < 64; ++p) {
    const int i = p >> 3, j = p & 7;
    const int cur = i & 1, prv = cur ^ 1;

    if (role == 0) {
      // ---- y-epilogue of pixel p-1 (mu/ls raw sums from xchg) ----
      if (p > 0) {
        const int pp = p - 1, ipp = pp >> 3, jpp = pp & 7;
        const float4 m4 = *reinterpret_cast<const float4*>(&xchg[pp & 1][0][0]);
        const float4 l4 = *reinterpret_cast<const float4*>(&xchg[pp & 1][1][0]);
        float y0 = (xls[0*64+pp] - (m4.x + boM[0])) / (expf(0.5f*(l4.x + boL[0])) + 1e-12f);
        float y1 = (xls[1*64+pp] - (m4.y + boM[1])) / (expf(0.5f*(l4.y + boL[1])) + 1e-12f);
        float y2 = (xls[2*64+pp] - (m4.z + boM[2])) / (expf(0.5f*(l4.z + boL[2])) + 1e-12f);
        float y3 = (xls[3*64+pp] - (m4.w + boM[3])) / (expf(0.5f*(l4.w + boL[3])) + 1e-12f);
        if (ch == 0) {
          float4 yv = make_float4(y0, y1, y2, y3);
          *reinterpret_cast<float4*>(&yb[net][ipp+1][jpp+1][0]) = yv;
        }
        if (net == 0 && ch < 4) {
          float ysel = ch == 0 ? y0 : (ch == 1 ? y1 : (ch == 2 ? y2 : y3));
          out[(b*4 + ch)*64 + pp] = ysel;
        }
      }
      // ---- h0(p): mask-A conv over y (4 taps x 4 in-ch, broadcast reads) ----
      float acc0 = bA;
#pragma unroll
      for (int t = 0; t < 4; ++t) {
        const float4 yv = *reinterpret_cast<const float4*>(&yb[net][i + KH[t]][j + KW[t]][0]);
        acc0 += waux[t*4+0]*yv.x + waux[t*4+1]*yv.y
              + waux[t*4+2]*yv.z + waux[t*4+3]*yv.w;
      }
      const float h0v = elu(acc0);
      h0row[net][cur][j + 1][ch] = h0v;

      // ---- W1: 4 off-center taps (LDS frags + readlane) + center (reg readlane) ----
      float a0 = bB, a1 = 0.f, a2 = 0.f, a3 = 0.f;
      const float4 fNW = reinterpret_cast<const float4*>(&h0row[net][prv][j    ][0])[ch & 15];
      const float4 fN  = reinterpret_cast<const float4*>(&h0row[net][prv][j + 1][0])[ch & 15];
      const float4 fNE = reinterpret_cast<const float4*>(&h0row[net][prv][j + 2][0])[ch & 15];
      const float4 fW  = reinterpret_cast<const float4*>(&h0row[net][cur][j    ][0])[ch & 15];
#pragma unroll
      for (int q = 0; q < 16; ++q) {
        a0 += wt[0][4*q+0]*rdlane(fNW.x,q) + wt[0][4*q+1]*rdlane(fNW.y,q)
            + wt[0][4*q+2]*rdlane(fNW.z,q) + wt[0][4*q+3]*rdlane(fNW.w,q);
        a1 += wt[1][4*q+0]*rdlane(fN.x,q)  + wt[1][4*q+1]*rdlane(fN.y,q)
            + wt[1][4*q+2]*rdlane(fN.z,q)  + wt[1][4*q+3]*rdlane(fN.w,q);
        a2 += wt[2][4*q+0]*rdlane(fNE.x,q) + wt[2][4*q+1]*rdlane(fNE.y,q)
            + wt[2][4*q+2]*rdlane(fNE.z,q) + wt[2][4*q+3]*rdlane(fNE.w,q);
        a3 += wt[3][4*q+0]*rdlane(fW.x,q)  + wt[3][4*q+1]*rdlane(fW.y,q)
            + wt[3][4*q+2]*rdlane(fW.z,q)  + wt[3][4*q+3]*rdlane(fW.w,q);
      }
      // center: h0(p) lives in this wave's lanes -> readlane from the register
#pragma unroll
      for (int q = 0; q < 64; q += 4) {
        a0 += wc[q+0]*rdlane(h0v, q+0);
        a1 += wc[q+1]*rdlane(h0v, q+1);
        a2 += wc[q+2]*rdlane(h0v, q+2);
        a3 += wc[q+3]*rdlane(h0v, q+3);
      }
      const float h1v = elu((a0 + a1) + (a2 + a3));
      h1row[net][cur][j + 1][ch] = h1v;
    } else {
      // ---- role1 pre-B1: W2 off-center taps vs h1 at pixels < p ----
      float a0 = bA, a1 = 0.f, a2 = 0.f, a3 = 0.f;
      const float4 fNW = reinterpret_cast<const float4*>(&h1row[net][prv][j    ][0])[ch & 15];
      const float4 fN  = reinterpret_cast<const float4*>(&h1row[net][prv][j + 1][0])[ch & 15];
      const float4 fNE = reinterpret_cast<const float4*>(&h1row[net][prv][j + 2][0])[ch & 15];
      const float4 fW  = reinterpret_cast<const float4*>(&h1row[net][cur][j    ][0])[ch & 15];
#pragma unroll
      for (int q = 0; q < 16; ++q) {
        a0 += wt[0][4*q+0]*rdlane(fNW.x,q) + wt[0][4*q+1]*rdlane(fNW.y,q)
            + wt[0][4*q+2]*rdlane(fNW.z,q) + wt[0][4*q+3]*rdlane(fNW.w,q);
        a1 += wt[1][4*q+0]*rdlane(fN.x,q)  + wt[1][4*q+1]*rdlane(fN.y,q)
            + wt[1][4*q+2]*rdlane(fN.z,q)  + wt[1][4*q+3]*rdlane(fN.w,q);
        a2 += wt[2][4*q+0]*rdlane(fNE.x,q) + wt[2][4*q+1]*rdlane(fNE.y,q)
            + wt[2][4*q+2]*rdlane(fNE.z,q) + wt[2][4*q+3]*rdlane(fNE.w,q);
        a3 += wt[3][4*q+0]*rdlane(fW.x,q)  + wt[3][4*q+1]*rdlane(fW.y,q)
            + wt[3][4*q+2]*rdlane(fW.z,q)  + wt[3][4*q+3]*rdlane(fW.w,q);
      }
      offacc = (a0 + a1) + (a2 + a3);
    }

    __syncthreads();   // B1: h1(p) visible to role1

    if (role == 1) {
      const float4 fc = reinterpret_cast<const float4*>(&h1row[net][cur][j + 1][0])[ch & 15];
      float a0 = offacc, a1 = 0.f, a2 = 0.f, a3 = 0.f;
#pragma unroll
      for (int q = 0; q < 16; ++q) {
        a0 += wc[4*q+0]*rdlane(fc.x,q);
        a1 += wc[4*q+1]*rdlane(fc.y,q);
        a2 += wc[4*q+2]*rdlane(fc.z,q);
        a3 += wc[4*q+3]*rdlane(fc.w,q);
      }
      const float h2 = elu((a0 + a1) + (a2 + a3));
      // 1x1 out conv: butterfly over the wave
      float s0 = waux[0]*h2, s1 = waux[1]*h2, s2 = waux[2]*h2, s3 = waux[3]*h2;
#pragma unroll
      for (int off = 32; off; off >>= 1) {
        s0 += __shfl_xor(s0, off, 64);
        s1 += __shfl_xor(s1, off, 64);
        s2 += __shfl_xor(s2, off, 64);
        s3 += __shfl_xor(s3, off, 64);
      }
      if (ch == 0) {
        float4 sv = make_float4(s0, s1, s2, s3);
        *reinterpret_cast<float4*>(&xchg[p & 1][net][0]) = sv;
      }
      if (net == 1 && ch == 0)
        lsacc += 0.5f*((s0 + boL[0]) + (s1 + boL[1]) + (s2 + boL[2]) + (s3 + boL[3]));
    }

    __syncthreads();   // B2: mu/ls(p) visible to role0 for next pixel
  }

  // final epilogue: pixel 63 output (no further pixels need y)
  if (role == 0 && net == 0 && ch < 4) {
    const int pp = 63;
    const float4 m4 = *reinterpret_cast<const float4*>(&xchg[pp & 1][0][0]);
    const float4 l4 = *reinterpret_cast<const float4*>(&xchg[pp & 1][1][0]);
    float mc = ch == 0 ? m4.x : (ch == 1 ? m4.y : (ch == 2 ? m4.z : m4.w));
    float lc = ch == 0 ? l4.x : (ch == 1 ? l4.y : (ch == 2 ? l4.z : l4.w));
    float bm = ch == 0 ? boM[0] : (ch == 1 ? boM[1] : (ch == 2 ? boM[2] : boM[3]));
    float bl = ch == 0 ? boL[0] : (ch == 1 ? boL[1] : (ch == 2 ? boL[2] : boL[3]));
    float yv = (xls[ch*64 + pp] - (mc + bm)) / (expf(0.5f*(lc + bl)) + 1e-12f);
    out[(b*4 + ch)*64 + pp] = yv;
  }
  if (role == 1 && net == 1 && ch == 0) out[32*4*64 + b] = lsacc;
}

extern "C" void kernel_launch(void* const* d_in, const int* in_sizes, int n_in,
                              void* d_out, int out_size, void* d_ws, size_t ws_size,
                              hipStream_t stream) {
  (void)in_sizes; (void)n_in; (void)out_size; (void)d_ws; (void)ws_size;
  made_ar_decode_k<<<dim3(32), dim3(NT), 0, stream>>>(
      (const float*)d_in[0],
      (const float*)d_in[1],  (const float*)d_in[2],
      (const float*)d_in[3],  (const float*)d_in[4],
      (const float*)d_in[5],  (const float*)d_in[6],
      (const float*)d_in[7],  (const float*)d_in[8],
      (const float*)d_in[9],  (const float*)d_in[10],
      (const float*)d_in[11], (const float*)d_in[12],
      (const float*)d_in[13], (const float*)d_in[14],
      (const float*)d_in[15], (const float*)d_in[16],
      (float*)d_out);
}

// Round 7
// 226.399 us; speedup vs baseline: 2.0401x; 2.0401x over previous
//
#include <hip/hip_runtime.h>

// MADE / PixelCNN autoregressive inverse (all fp32, per reference).
//
// Rounds 0-4: six-phase/16-wave skeleton stuck at ~179us (~6700 cy/pixel)
// regardless of inner-loop implementation -> skeleton(barrier/latency)-bound.
// Round 5: 2-barrier/4-wave restructure was correct (passed) but put 336
// pinned floats/thread against a 256-VGPR cap -> real scratch spills
// (WRITE_SIZE 2465 KB), 384us.
// Round 6: same design, legal budgeting -- died on a macro bug: DOT16's
// parameter `w` collided with float4 member `.w` ((f).w -> (f0).wNE).
// Round 7 = round 6 with macro params renamed (W_, F_). No design change.
//
//  * 8 waves (NT=512, 2/SIMD, 256-VGPR cap), per net: S + 3 helpers.
//  * Per-role register arrays declared in DISJOINT SCOPES (each role has its
//    own pixel loop) so the allocator overlays them; max pinned = 192+temps.
//  * 2 raw s_barriers per pixel in EVERY wave's loop (producer/consumer
//    pattern; s_barrier has no same-PC requirement).
//  * No global stores in the loop: y kept in LDS, copied out at the end.
// Roles per net (lane = out channel):
//  S : w0row[16] + W1-center[64] + W2-center[64] + wo[4]. Pre-B1: y(p-1)
//      epilogue + h0(p). Post-B1: h1 = elu(b1+red1a+red1b+center.h0) via
//      readlane chain on own h0v; h2 likewise on own h1v; 1x1 out-conv
//      butterfly; writes xchg.
//  Ha: W1 {NW,N,NE} columns vs h0 row i-1          -> red1a.
//  Hb: W1 {W} vs h0(p-1) + W2 {NW,N} vs h1 row i-1 -> red1b, red2b.
//  Hc: W2 {NE} vs h1 row i-1 + W2 {W} vs h1(p-1)   -> red2c.
// LDS pad columns (never written, stay 0) give zero W-taps at j==0 for free.

#define NT 512

__device__ __forceinline__ float elu(float x) { return x > 0.f ? x : expm1f(x); }

__device__ __forceinline__ float rdlane(float v, int l) {
  return __int_as_float(__builtin_amdgcn_readlane(__float_as_int(v), l));
}

#define BAR() asm volatile("s_waitcnt lgkmcnt(0)\n\ts_barrier" ::: "memory")

// one 64-dot quarter-step: acc{0..3} += W_[4q+m] * (lane-q broadcast of F_ members)
#define DOT16(W_, F_)                                                \
  _Pragma("unroll")                                                  \
  for (int q = 0; q < 16; ++q) {                                     \
    a0 += (W_)[4*q+0] * rdlane((F_).x, q);                           \
    a1 += (W_)[4*q+1] * rdlane((F_).y, q);                           \
    a2 += (W_)[4*q+2] * rdlane((F_).z, q);                           \
    a3 += (W_)[4*q+3] * rdlane((F_).w, q);                           \
  }

__global__ __launch_bounds__(NT)
__attribute__((amdgpu_waves_per_eu(2, 2)))
void made_ar_decode_k(
    const float* __restrict__ x,
    const float* __restrict__ mw0, const float* __restrict__ mb0,
    const float* __restrict__ mw1, const float* __restrict__ mb1,
    const float* __restrict__ mw2, const float* __restrict__ mb2,
    const float* __restrict__ mwo, const float* __restrict__ mbo,
    const float* __restrict__ lw0, const float* __restrict__ lb0,
    const float* __restrict__ lw1, const float* __restrict__ lb1,
    const float* __restrict__ lw2, const float* __restrict__ lb2,
    const float* __restrict__ lwo, const float* __restrict__ lbo,
    float* __restrict__ out)
{
  const int b    = blockIdx.x;
  const int tid  = threadIdx.x;
  const int wave = tid >> 6;       // 0..7
  const int role = wave >> 1;      // 0:S  1:Ha  2:Hb  3:Hc
  const int net  = wave & 1;       // 0 = mu, 1 = lv
  const int ch   = tid & 63;       // lane == out channel

  // row caches, parity double-buffered; col index = spatial col + 1;
  // pad cols 0 and 9 are never written -> permanent zeros ('SAME' border).
  __shared__ __align__(16) float h0row[2][2][10][64]; // [net][par][col+1][ch]
  __shared__ __align__(16) float h1row[2][2][10][64];
  __shared__ __align__(16) float yb[2][9][10][4];     // [net][row+1][col+1][c]
  __shared__ __align__(16) float xchg[2][2][4];       // [p&1][net][c] raw sums
  __shared__ float red1a[2][64], red1b[2][64], red2b[2][64], red2c[2][64];
  __shared__ float xls[256];

  for (int k = tid; k < 2*2*10*64; k += NT) {
    (&h0row[0][0][0][0])[k] = 0.f;
    (&h1row[0][0][0][0])[k] = 0.f;
  }
  for (int k = tid; k < 2*9*10*4; k += NT) (&yb[0][0][0][0])[k] = 0.f;
  if (tid < 256) xls[tid] = x[b*256 + tid];   // [c][i][j] flat = c*64 + p

  __syncthreads();   // uniform join after init

  if (role == 0) {
    // ================= S: spine =================
    const float* w0g = net ? lw0 : mw0;
    const float* w1g = net ? lw1 : mw1;
    const float* w2g = net ? lw2 : mw2;
    const float* wog = net ? lwo : mwo;
    const int KH[4] = {0,0,0,1};
    const int KW[4] = {0,1,2,0};
    float waux[16], wc1[64], wc2[64], wo4[4];
#pragma unroll
    for (int t = 0; t < 4; ++t)
#pragma unroll
      for (int ic = 0; ic < 4; ++ic)
        waux[t*4 + ic] = w0g[((ch*4 + ic)*3 + KH[t])*3 + KW[t]];
#pragma unroll
    for (int q = 0; q < 64; ++q) wc1[q] = w1g[((ch*64 + q)*3 + 1)*3 + 1];
#pragma unroll
    for (int q = 0; q < 64; ++q) wc2[q] = w2g[((ch*64 + q)*3 + 1)*3 + 1];
#pragma unroll
    for (int c = 0; c < 4; ++c) wo4[c] = wog[c*64 + ch];
    float bA = (net ? lb0 : mb0)[ch];
    float bB = (net ? lb1 : mb1)[ch];
    float bC = (net ? lb2 : mb2)[ch];
    float boM[4], boL[4];
#pragma unroll
    for (int c = 0; c < 4; ++c) { boM[c] = mbo[c]; boL[c] = lbo[c]; }
#pragma unroll
    for (int k = 0; k < 16; ++k) asm volatile("" : "+v"(waux[k]));
#pragma unroll
    for (int q = 0; q < 64; ++q) asm volatile("" : "+v"(wc1[q]));
#pragma unroll
    for (int q = 0; q < 64; ++q) asm volatile("" : "+v"(wc2[q]));

    float lsacc = 0.f;

#pragma unroll 1
    for (int p = 0; p < 64; ++p) {
      const int i = p >> 3, j = p & 7, cur = i & 1;

      // ---- pre-B1: y-epilogue of p-1, then h0(p) ----
      if (p > 0) {
        const int pp = p - 1;
        const float4 m4 = *reinterpret_cast<const float4*>(&xchg[pp & 1][0][0]);
        const float4 l4 = *reinterpret_cast<const float4*>(&xchg[pp & 1][1][0]);
        float y0 = (xls[0*64+pp] - (m4.x + boM[0])) / (expf(0.5f*(l4.x + boL[0])) + 1e-12f);
        float y1 = (xls[1*64+pp] - (m4.y + boM[1])) / (expf(0.5f*(l4.y + boL[1])) + 1e-12f);
        float y2 = (xls[2*64+pp] - (m4.z + boM[2])) / (expf(0.5f*(l4.z + boL[2])) + 1e-12f);
        float y3 = (xls[3*64+pp] - (m4.w + boM[3])) / (expf(0.5f*(l4.w + boL[3])) + 1e-12f);
        if (ch == 0)
          *reinterpret_cast<float4*>(&yb[net][(pp>>3)+1][(pp&7)+1][0]) =
              make_float4(y0, y1, y2, y3);
      }
      float acc = bA;
#pragma unroll
      for (int t = 0; t < 4; ++t) {
        const float4 yv = *reinterpret_cast<const float4*>(&yb[net][i + KH[t]][j + KW[t]][0]);
        acc += waux[t*4+0]*yv.x + waux[t*4+1]*yv.y
             + waux[t*4+2]*yv.z + waux[t*4+3]*yv.w;
      }
      const float h0v = elu(acc);
      h0row[net][cur][j + 1][ch] = h0v;

      BAR();   // B1: h0(p) + all helper partials visible

      // ---- post-B1: h1 -> h2 -> out-conv ----
      float a0 = 0.f, a1 = 0.f, a2 = 0.f, a3 = 0.f;
#pragma unroll
      for (int q = 0; q < 16; ++q) {
        a0 += wc1[4*q+0] * rdlane(h0v, 4*q+0);
        a1 += wc1[4*q+1] * rdlane(h0v, 4*q+1);
        a2 += wc1[4*q+2] * rdlane(h0v, 4*q+2);
        a3 += wc1[4*q+3] * rdlane(h0v, 4*q+3);
      }
      const float h1v = elu(((a0 + a1) + (a2 + a3)) + bB
                            + red1a[net][ch] + red1b[net][ch]);
      h1row[net][cur][j + 1][ch] = h1v;

      a0 = 0.f; a1 = 0.f; a2 = 0.f; a3 = 0.f;
#pragma unroll
      for (int q = 0; q < 16; ++q) {
        a0 += wc2[4*q+0] * rdlane(h1v, 4*q+0);
        a1 += wc2[4*q+1] * rdlane(h1v, 4*q+1);
        a2 += wc2[4*q+2] * rdlane(h1v, 4*q+2);
        a3 += wc2[4*q+3] * rdlane(h1v, 4*q+3);
      }
      const float h2v = elu(((a0 + a1) + (a2 + a3)) + bC
                            + red2b[net][ch] + red2c[net][ch]);

      float s0 = wo4[0]*h2v, s1 = wo4[1]*h2v, s2 = wo4[2]*h2v, s3 = wo4[3]*h2v;
#pragma unroll
      for (int off = 32; off; off >>= 1) {
        s0 += __shfl_xor(s0, off, 64);
        s1 += __shfl_xor(s1, off, 64);
        s2 += __shfl_xor(s2, off, 64);
        s3 += __shfl_xor(s3, off, 64);
      }
      if (ch == 0)
        *reinterpret_cast<float4*>(&xchg[p & 1][net][0]) = make_float4(s0, s1, s2, s3);
      if (net == 1 && ch == 0)
        lsacc += 0.5f*((s0 + boL[0]) + (s1 + boL[1]) + (s2 + boL[2]) + (s3 + boL[3]));

      BAR();   // B2: h1(p), xchg(p) visible for next pixel
    }

    // final y(63) into yb (for the copy-out)
    {
      const float4 m4 = *reinterpret_cast<const float4*>(&xchg[1][0][0]);
      const float4 l4 = *reinterpret_cast<const float4*>(&xchg[1][1][0]);
      float y0 = (xls[0*64+63] - (m4.x + boM[0])) / (expf(0.5f*(l4.x + boL[0])) + 1e-12f);
      float y1 = (xls[1*64+63] - (m4.y + boM[1])) / (expf(0.5f*(l4.y + boL[1])) + 1e-12f);
      float y2 = (xls[2*64+63] - (m4.z + boM[2])) / (expf(0.5f*(l4.z + boL[2])) + 1e-12f);
      float y3 = (xls[3*64+63] - (m4.w + boM[3])) / (expf(0.5f*(l4.w + boL[3])) + 1e-12f);
      if (ch == 0)
        *reinterpret_cast<float4*>(&yb[net][8][8][0]) = make_float4(y0, y1, y2, y3);
    }
    if (net == 1 && ch == 0) out[32*4*64 + b] = lsacc;

  } else if (role == 1) {
    // ================= Ha: W1 {NW, N, NE} vs h0 row i-1 =================
    const float* w1g = net ? lw1 : mw1;
    float wNW[64], wN[64], wNE[64];
#pragma unroll
    for (int q = 0; q < 64; ++q) {
      wNW[q] = w1g[((ch*64 + q)*3 + 0)*3 + 0];
      wN [q] = w1g[((ch*64 + q)*3 + 0)*3 + 1];
      wNE[q] = w1g[((ch*64 + q)*3 + 0)*3 + 2];
    }
#pragma unroll
    for (int q = 0; q < 64; ++q) {
      asm volatile("" : "+v"(wNW[q]));
      asm volatile("" : "+v"(wN[q]));
      asm volatile("" : "+v"(wNE[q]));
    }
#pragma unroll 1
    for (int p = 0; p < 64; ++p) {
      const int i = p >> 3, j = p & 7, prv = (i & 1) ^ 1;
      const float4 f0 = reinterpret_cast<const float4*>(&h0row[net][prv][j    ][0])[ch & 15];
      const float4 f1 = reinterpret_cast<const float4*>(&h0row[net][prv][j + 1][0])[ch & 15];
      const float4 f2 = reinterpret_cast<const float4*>(&h0row[net][prv][j + 2][0])[ch & 15];
      float a0 = 0.f, a1 = 0.f, a2 = 0.f, a3 = 0.f;
      DOT16(wNW, f0);
      DOT16(wN,  f1);
      DOT16(wNE, f2);
      red1a[net][ch] = (a0 + a1) + (a2 + a3);
      BAR();
      BAR();
    }

  } else if (role == 2) {
    // ====== Hb: W1 {W} vs h0(p-1)  +  W2 {NW, N} vs h1 row i-1 ======
    const float* w1g = net ? lw1 : mw1;
    const float* w2g = net ? lw2 : mw2;
    float wW1[64], wNW[64], wN[64];
#pragma unroll
    for (int q = 0; q < 64; ++q) {
      wW1[q] = w1g[((ch*64 + q)*3 + 1)*3 + 0];
      wNW[q] = w2g[((ch*64 + q)*3 + 0)*3 + 0];
      wN [q] = w2g[((ch*64 + q)*3 + 0)*3 + 1];
    }
#pragma unroll
    for (int q = 0; q < 64; ++q) {
      asm volatile("" : "+v"(wW1[q]));
      asm volatile("" : "+v"(wNW[q]));
      asm volatile("" : "+v"(wN[q]));
    }
#pragma unroll 1
    for (int p = 0; p < 64; ++p) {
      const int i = p >> 3, j = p & 7, cur = i & 1, prv = cur ^ 1;
      const float4 fW = reinterpret_cast<const float4*>(&h0row[net][cur][j    ][0])[ch & 15];
      const float4 f0 = reinterpret_cast<const float4*>(&h1row[net][prv][j    ][0])[ch & 15];
      const float4 f1 = reinterpret_cast<const float4*>(&h1row[net][prv][j + 1][0])[ch & 15];
      {
        float a0 = 0.f, a1 = 0.f, a2 = 0.f, a3 = 0.f;
        DOT16(wW1, fW);
        red1b[net][ch] = (a0 + a1) + (a2 + a3);
      }
      {
        float a0 = 0.f, a1 = 0.f, a2 = 0.f, a3 = 0.f;
        DOT16(wNW, f0);
        DOT16(wN,  f1);
        red2b[net][ch] = (a0 + a1) + (a2 + a3);
      }
      BAR();
      BAR();
    }

  } else {
    // ====== Hc: W2 {NE} vs h1 row i-1  +  W2 {W} vs h1(p-1) ======
    const float* w2g = net ? lw2 : mw2;
    float wNE[64], wW2[64];
#pragma unroll
    for (int q = 0; q < 64; ++q) {
      wNE[q] = w2g[((ch*64 + q)*3 + 0)*3 + 2];
      wW2[q] = w2g[((ch*64 + q)*3 + 1)*3 + 0];
    }
#pragma unroll
    for (int q = 0; q < 64; ++q) {
      asm volatile("" : "+v"(wNE[q]));
      asm volatile("" : "+v"(wW2[q]));
    }
#pragma unroll 1
    for (int p = 0; p < 64; ++p) {
      const int i = p >> 3, j = p & 7, cur = i & 1, prv = cur ^ 1;
      const float4 f0 = reinterpret_cast<const float4*>(&h1row[net][prv][j + 2][0])[ch & 15];
      const float4 f1 = reinterpret_cast<const float4*>(&h1row[net][cur][j    ][0])[ch & 15];
      float a0 = 0.f, a1 = 0.f, a2 = 0.f, a3 = 0.f;
      DOT16(wNE, f0);
      DOT16(wW2, f1);
      red2c[net][ch] = (a0 + a1) + (a2 + a3);
      BAR();
      BAR();
    }
  }

  BAR();   // join: yb complete (incl. y(63))

  // copy-out: y from yb[0]
  if (tid < 256) {
    const int c = tid >> 6, p = tid & 63;
    out[(b*4 + c)*64 + p] = yb[0][(p >> 3) + 1][(p & 7) + 1][c];
  }
}

extern "C" void kernel_launch(void* const* d_in, const int* in_sizes, int n_in,
                              void* d_out, int out_size, void* d_ws, size_t ws_size,
                              hipStream_t stream) {
  (void)in_sizes; (void)n_in; (void)out_size; (void)d_ws; (void)ws_size;
  made_ar_decode_k<<<dim3(32), dim3(NT), 0, stream>>>(
      (const float*)d_in[0],
      (const float*)d_in[1],  (const float*)d_in[2],
      (const float*)d_in[3],  (const float*)d_in[4],
      (const float*)d_in[5],  (const float*)d_in[6],
      (const float*)d_in[7],  (const float*)d_in[8],
      (const float*)d_in[9],  (const float*)d_in[10],
      (const float*)d_in[11], (const float*)d_in[12],
      (const float*)d_in[13], (const float*)d_in[14],
      (const float*)d_in[15], (const float*)d_in[16],
      (float*)d_out);
}